// Round 1
// baseline (2276.203 us; speedup 1.0000x reference)
//
#include <hip/hip_runtime.h>

// Problem constants (from setup_inputs): B=16, C=64, H=W=128, OUT=64
#define IMG_H 128
#define IMG_W 128
#define C_IN  64
#define HW    16384

// Tiled direct 3x3 conv, stride 1, pad 1, NCHW/OIHW, fp32.
// Block: 16x16 threads; each thread computes 2x2 output pixels x 8 output
// channels => 32x32 output tile, 8 ocs per block.
// Loop over input channels in chunks of 8, staging a 34x34 halo tile in LDS.
template<int OCG, bool BIAS>
__global__ __launch_bounds__(256) void conv3x3_k(
    const float* __restrict__ x, const float* __restrict__ w,
    const float* __restrict__ bias, float* __restrict__ out)
{
    __shared__ float xs[8][34 * 34];   // 36992 B
    __shared__ float wsm[8][9][8];     // [ic][k][oc] 2304 B

    const int tx = threadIdx.x, ty = threadIdx.y;
    const int tid = ty * 16 + tx;
    const int bx = blockIdx.x, by = blockIdx.y;
    const int b  = (int)blockIdx.z / OCG;
    const int og = (int)blockIdx.z % OCG;
    const int oc0 = og * 8;
    const int OC = OCG * 8;

    float acc[8][2][2] = {};

    const int row0 = by * 32 - 1, col0 = bx * 32 - 1;

    for (int ic0 = 0; ic0 < C_IN; ic0 += 8) {
        // ---- stage input halo tile (8 ch x 34 x 34) ----
        for (int i = tid; i < 8 * 1156; i += 256) {
            int ic = i / 1156, p = i - ic * 1156;
            int r = p / 34, cc = p - r * 34;
            int gr = row0 + r, gc = col0 + cc;
            float v = 0.f;
            if ((unsigned)gr < 128u && (unsigned)gc < 128u)
                v = x[((b * C_IN + ic0 + ic) * IMG_H + gr) * IMG_W + gc];
            xs[ic][p] = v;
        }
        // ---- stage weights (8 oc x 8 ic x 9) ----
        for (int i = tid; i < 576; i += 256) {
            int o = i / 72, rem = i - o * 72;
            int ic = rem / 9, k = rem - ic * 9;
            wsm[ic][k][o] = w[((oc0 + o) * C_IN + ic0 + ic) * 9 + k];
        }
        __syncthreads();

        #pragma unroll
        for (int ic = 0; ic < 8; ++ic) {
            // 4x4 input window for this thread's 2x2 outputs
            float xw[4][4];
            #pragma unroll
            for (int i = 0; i < 4; ++i) {
                const float2 a0 = *(const float2*)&xs[ic][(2 * ty + i) * 34 + 2 * tx];
                const float2 a1 = *(const float2*)&xs[ic][(2 * ty + i) * 34 + 2 * tx + 2];
                xw[i][0] = a0.x; xw[i][1] = a0.y; xw[i][2] = a1.x; xw[i][3] = a1.y;
            }
            #pragma unroll
            for (int k = 0; k < 9; ++k) {
                const int ky = k / 3, kx = k - ky * 3;
                const float4 w0 = *(const float4*)&wsm[ic][k][0];
                const float4 w1 = *(const float4*)&wsm[ic][k][4];
                const float wv[8] = {w0.x, w0.y, w0.z, w0.w, w1.x, w1.y, w1.z, w1.w};
                #pragma unroll
                for (int py = 0; py < 2; ++py)
                    #pragma unroll
                    for (int px = 0; px < 2; ++px) {
                        const float xv = xw[py + ky][px + kx];
                        #pragma unroll
                        for (int o = 0; o < 8; ++o)
                            acc[o][py][px] = fmaf(xv, wv[o], acc[o][py][px]);
                    }
            }
        }
        __syncthreads();
    }

    const int orow = by * 32 + 2 * ty, ocol = bx * 32 + 2 * tx;
    #pragma unroll
    for (int o = 0; o < 8; ++o) {
        const float bb = BIAS ? bias[oc0 + o] : 0.f;
        #pragma unroll
        for (int py = 0; py < 2; ++py) {
            float2 v;
            v.x = acc[o][py][0] + bb;
            v.y = acc[o][py][1] + bb;
            *(float2*)&out[(((size_t)b * OC + oc0 + o) * IMG_H + orow + py) * IMG_W + ocol] = v;
        }
    }
}

// Bilinear deformable gather.
// off is the conv1 output in (B, 2C, H, W) flat layout. Per the reference's
// raw reshape (B*C, H*W, 2): offsets for (b,c,hw) are at
// off[b*2C*HW + c*2*HW + 2*hw + {0,1}] = off[(bc<<15) + 2*hw + {0,1}].
__global__ __launch_bounds__(256) void deform_k(
    const float* __restrict__ x, const float* __restrict__ off,
    float* __restrict__ mapped)
{
    const int idx = blockIdx.x * 256 + threadIdx.x;     // 16*64*16384 total
    const int bc = idx >> 14;
    const int hw = idx & 16383;
    const int h = hw >> 7, wc = hw & 127;

    const float2 o2 = *(const float2*)&off[((size_t)bc << 15) + 2 * hw];
    const float rr = fminf(fmaxf(o2.x + (float)h, 0.f), 127.f);
    const float cc = fminf(fmaxf(o2.y + (float)wc, 0.f), 127.f);
    const float r0f = floorf(rr), c0f = floorf(cc);
    const float r1f = ceilf(rr),  c1f = ceilf(cc);
    const int r0 = (int)r0f, r1 = (int)r1f;
    const int c0 = (int)c0f, c1 = (int)c1f;

    const float* xp = x + ((size_t)bc << 14);
    const float v_lt = xp[(r0 << 7) + c0];
    const float v_rt = xp[(r1 << 7) + c0];
    const float v_lb = xp[(r0 << 7) + c1];
    const float v_rb = xp[(r1 << 7) + c1];

    const float fr = rr - r0f, fc = cc - c0f;
    const float vt = fr * (v_rt - v_lt) + v_lt;
    const float vb = fr * (v_rb - v_lb) + v_lb;
    mapped[idx] = fc * (vb - vt) + vt;
}

extern "C" void kernel_launch(void* const* d_in, const int* in_sizes, int n_in,
                              void* d_out, int out_size, void* d_ws, size_t ws_size,
                              hipStream_t stream) {
    const float* x      = (const float*)d_in[0];   // (16,64,128,128)
    const float* w_off  = (const float*)d_in[1];   // (128,64,3,3)
    const float* w_conv = (const float*)d_in[2];   // (64,64,3,3)
    const float* b_conv = (const float*)d_in[3];   // (64,)
    float* out = (float*)d_out;                    // (16,64,128,128)

    float* off    = (float*)d_ws;                  // 33,554,432 floats (128 MiB)
    float* mapped = off + 33554432;                // 16,777,216 floats (64 MiB)

    // conv1: OC=128 -> OCG=16; grid.z = B*OCG = 256
    conv3x3_k<16, false><<<dim3(4, 4, 256), dim3(16, 16), 0, stream>>>(
        x, w_off, nullptr, off);

    // deform: 16,777,216 elements
    deform_k<<<65536, 256, 0, stream>>>(x, off, mapped);

    // conv2: OC=64 -> OCG=8; grid.z = B*OCG = 128
    conv3x3_k<8, true><<<dim3(4, 4, 128), dim3(16, 16), 0, stream>>>(
        mapped, w_conv, b_conv, out);
}

// Round 2
// 351.440 us; speedup vs baseline: 6.4768x; 6.4768x over previous
//
#include <hip/hip_runtime.h>

typedef _Float16 f16;
typedef _Float16 half8 __attribute__((ext_vector_type(8)));
typedef float f32x4 __attribute__((ext_vector_type(4)));
typedef int i32x4 __attribute__((ext_vector_type(4)));

// Problem constants: B=16, C=64, H=W=128, OUT=64, HW=16384

// ---------------- weight packing: OIHW fp32 -> [tap][oc][ic] f16 ----------------
__global__ __launch_bounds__(256) void pack_w_k(
    const float* __restrict__ w_off, const float* __restrict__ w_conv,
    f16* __restrict__ W1p, f16* __restrict__ W2p)
{
    int t = blockIdx.x * 256 + threadIdx.x;   // 432*256 = 110592 = 73728 + 36864
    if (t < 73728) {
        int tap = t >> 13, oc = (t >> 6) & 127, ic = t & 63;
        W1p[t] = (f16)w_off[(oc * 64 + ic) * 9 + tap];
    } else {
        int t2 = t - 73728;
        int tap = t2 >> 12, oc = (t2 >> 6) & 63, ic = t2 & 63;
        W2p[t2] = (f16)w_conv[(oc * 64 + ic) * 9 + tap];
    }
}

// ---------------- x NCHW fp32 -> xT NHWC f16 ----------------
__global__ __launch_bounds__(256) void transpose_k(
    const float* __restrict__ x, f16* __restrict__ xT)
{
    __shared__ float lds[64 * 132];
    const int b = blockIdx.x >> 7, h = blockIdx.x & 127;
    const int tid = threadIdx.x;
    const float4* x4 = (const float4*)x;
    for (int i = tid; i < 2048; i += 256) {
        int ic = i >> 5, wq = i & 31;
        float4 v = x4[(b * 64 + ic) * 4096 + h * 32 + wq];
        *(float4*)&lds[ic * 132 + wq * 4] = v;
    }
    __syncthreads();
    for (int i = tid; i < 1024; i += 256) {
        int w = i & 127, kg = i >> 7;
        half8 hv;
        #pragma unroll
        for (int j = 0; j < 8; ++j) hv[j] = (f16)lds[(kg * 8 + j) * 132 + w];
        *(half8*)&xT[(((size_t)(b * 128 + h) * 128 + w) << 6) + kg * 8] = hv;
    }
}

// ---------------- implicit-GEMM 3x3 conv via MFMA ----------------
// src: [b][hw][64] f16 NHWC.  Wp: [9][OC][64] f16.  out: [b][OC][hw] f32.
// Block: 256 thr (4 waves), output tile OC_tile x 128 pix (one image row).
// WM x WN wave grid; wave tile = 64 oc x (128/WN) pix; m_rep=4, n_rep=128/WN/16.
// LDS: 3 rows x 130 cols x 64 ic f16, XOR-swizzled (byte ^= (c&7)<<4).
template<int OC, int WM, int WN, bool BIAS>
__global__ __launch_bounds__(256, 3) void conv_mfma_k(
    const f16* __restrict__ src, const f16* __restrict__ Wp,
    const float* __restrict__ bias, float* __restrict__ out)
{
    constexpr int NREP = 128 / WN / 16;
    __shared__ short xs[3 * 130 * 64];           // 49920 B
    char* xsb = (char*)xs;

    const int tid = threadIdx.x;
    const int h = blockIdx.x, b = blockIdx.y;

    // ---- stage halo tile, swizzled ----
    {
        const i32x4* s4 = (const i32x4*)src;
        for (int s = tid; s < 3120; s += 256) {   // 3*130*8 16B-slots
            int kg = s & 7, t = s >> 3;
            int c = t % 130, r = t / 130;
            int rowg = h + r - 1, wg = c - 1;
            i32x4 v = {0, 0, 0, 0};
            if ((unsigned)rowg < 128u && (unsigned)wg < 128u)
                v = s4[((b * 128 + rowg) * 128 + wg) * 8 + kg];
            int off = (t << 7) + (kg << 4);
            off ^= (c & 7) << 4;
            *(i32x4*)(xsb + off) = v;
        }
    }
    __syncthreads();

    const int lane = tid & 63, wv = tid >> 6;
    const int l15 = lane & 15, l4 = lane >> 4;
    const int wm = wv / WN, wn = wv % WN;
    const int pixb = wn * (128 / WN);
    const int ocb = wm * 64 + l15;

    f32x4 acc[4][NREP];
    #pragma unroll
    for (int m = 0; m < 4; ++m)
        #pragma unroll
        for (int n = 0; n < NREP; ++n) acc[m][n] = {0.f, 0.f, 0.f, 0.f};

    half8 a_cur[4], a_nxt[4];
    #pragma unroll
    for (int m = 0; m < 4; ++m)
        a_cur[m] = *(const half8*)&Wp[(0 * OC + ocb + m * 16) * 64 + l4 * 8];

    #pragma unroll
    for (int step = 0; step < 18; ++step) {
        const int tap = step >> 1, ks = step & 1;
        const int r = tap / 3, dxp = tap % 3;
        if (step < 17) {  // prefetch next step's A fragments (L2-resident weights)
            const int tap1 = (step + 1) >> 1, ks1 = (step + 1) & 1;
            #pragma unroll
            for (int m = 0; m < 4; ++m)
                a_nxt[m] = *(const half8*)&Wp[(tap1 * OC + ocb + m * 16) * 64 + ks1 * 32 + l4 * 8];
        }
        half8 bf[NREP];
        #pragma unroll
        for (int n = 0; n < NREP; ++n) {
            const int c = pixb + n * 16 + l15 + dxp;
            int off = ((r * 130 + c) << 7) + (ks << 6) + (l4 << 4);
            off ^= (c & 7) << 4;
            bf[n] = *(const half8*)(xsb + off);
        }
        #pragma unroll
        for (int m = 0; m < 4; ++m)
            #pragma unroll
            for (int n = 0; n < NREP; ++n)
                acc[m][n] = __builtin_amdgcn_mfma_f32_16x16x32_f16(
                    a_cur[m], bf[n], acc[m][n], 0, 0, 0);
        #pragma unroll
        for (int m = 0; m < 4; ++m) a_cur[m] = a_nxt[m];
    }

    // ---- store (C/D: col=lane&15=pix, row=(lane>>4)*4+i=oc) ----
    #pragma unroll
    for (int m = 0; m < 4; ++m) {
        #pragma unroll
        for (int i = 0; i < 4; ++i) {
            const int oc = wm * 64 + m * 16 + l4 * 4 + i;
            const float bb = BIAS ? bias[oc] : 0.f;
            #pragma unroll
            for (int n = 0; n < NREP; ++n) {
                const int pix = pixb + n * 16 + l15;
                out[(((size_t)b * OC + oc) << 14) + h * 128 + pix] = acc[m][n][i] + bb;
            }
        }
    }
}

// ---------------- bilinear deformable gather ----------------
// off: fp32 NCHW (B,128,HW) from conv1. Reference reshape => for (b,c,hw):
// row_off = off[(bc<<15) + 2*hw], col_off = off[(bc<<15) + 2*hw + 1].
// mapped: f16 NHWC [b][hw][64] via LDS transpose.
__global__ __launch_bounds__(256) void deform_k(
    const float* __restrict__ x, const float* __restrict__ off,
    f16* __restrict__ mapped)
{
    __shared__ float lds[64 * 65];
    const int tid = threadIdx.x;
    const int b = blockIdx.x >> 8, pix0 = (blockIdx.x & 255) << 6;
    const int lane = tid & 63, cgrp = tid >> 6;
    const int hw = pix0 + lane;
    const int h = hw >> 7, wc = hw & 127;

    #pragma unroll 4
    for (int j = 0; j < 16; ++j) {
        const int c = cgrp * 16 + j;
        const int bc = b * 64 + c;
        const float2 o2 = *(const float2*)&off[((size_t)bc << 15) + (hw << 1)];
        float rr = fminf(fmaxf(o2.x + (float)h, 0.f), 127.f);
        float cc = fminf(fmaxf(o2.y + (float)wc, 0.f), 127.f);
        float r0f = floorf(rr), c0f = floorf(cc);
        float r1f = ceilf(rr),  c1f = ceilf(cc);
        int r0 = (int)r0f, r1 = (int)r1f, c0 = (int)c0f, c1 = (int)c1f;
        const float* xp = x + ((size_t)bc << 14);
        float v_lt = xp[(r0 << 7) + c0];
        float v_rt = xp[(r1 << 7) + c0];
        float v_lb = xp[(r0 << 7) + c1];
        float v_rb = xp[(r1 << 7) + c1];
        float fr = rr - r0f, fc = cc - c0f;
        float vt = fr * (v_rt - v_lt) + v_lt;
        float vb = fr * (v_rb - v_lb) + v_lb;
        lds[lane * 65 + c] = fc * (vb - vt) + vt;
    }
    __syncthreads();
    for (int i = tid; i < 512; i += 256) {
        const int p = i & 63, kg = i >> 6;
        half8 hv;
        #pragma unroll
        for (int j = 0; j < 8; ++j) hv[j] = (f16)lds[p * 65 + kg * 8 + j];
        *(half8*)&mapped[(((size_t)(b << 14) + pix0 + p) << 6) + kg * 8] = hv;
    }
}

extern "C" void kernel_launch(void* const* d_in, const int* in_sizes, int n_in,
                              void* d_out, int out_size, void* d_ws, size_t ws_size,
                              hipStream_t stream) {
    const float* x      = (const float*)d_in[0];   // (16,64,128,128)
    const float* w_off  = (const float*)d_in[1];   // (128,64,3,3)
    const float* w_conv = (const float*)d_in[2];   // (64,64,3,3)
    const float* b_conv = (const float*)d_in[3];   // (64,)
    float* out = (float*)d_out;                    // (16,64,128,128)

    char* ws = (char*)d_ws;
    f16*   xT     = (f16*)ws;                            // 33,554,432 B
    f16*   mapped = xT;                                  // alias: xT dead after conv1
    float* off    = (float*)(ws + 33554432);             // 134,217,728 B
    f16*   W1p    = (f16*)(ws + 33554432 + 134217728);   // 147,456 B
    f16*   W2p    = (f16*)(ws + 33554432 + 134217728 + 147456); // 73,728 B

    pack_w_k<<<432, 256, 0, stream>>>(w_off, w_conv, W1p, W2p);
    transpose_k<<<2048, 256, 0, stream>>>(x, xT);
    // conv1: 128 oc, waves 2Mx2N (wave tile 64x64)
    conv_mfma_k<128, 2, 2, false><<<dim3(128, 16), 256, 0, stream>>>(xT, W1p, nullptr, off);
    deform_k<<<4096, 256, 0, stream>>>(x, off, mapped);
    // conv2: 64 oc, waves 1Mx4N (wave tile 64x32), + bias
    conv_mfma_k<64, 1, 4, true><<<dim3(128, 16), 256, 0, stream>>>(mapped, W2p, b_conv, out);
}

// Round 3
// 311.217 us; speedup vs baseline: 7.3139x; 1.1292x over previous
//
#include <hip/hip_runtime.h>

typedef _Float16 f16;
typedef _Float16 half8 __attribute__((ext_vector_type(8)));
typedef _Float16 f16x2 __attribute__((ext_vector_type(2)));
typedef float f32x4 __attribute__((ext_vector_type(4)));
typedef int i32x4 __attribute__((ext_vector_type(4)));
typedef unsigned short ushort_t;

// B=16, C=64, H=W=128, OUT=64, HW=16384

// ---------------- weight packing: OIHW fp32 -> [tap][oc][ic] f16 ----------------
__global__ __launch_bounds__(256) void pack_w_k(
    const float* __restrict__ w_off, const float* __restrict__ w_conv,
    f16* __restrict__ W1p, f16* __restrict__ W2p)
{
    int t = blockIdx.x * 256 + threadIdx.x;   // 432*256 = 110592 = 73728 + 36864
    if (t < 73728) {
        int tap = t >> 13, oc = (t >> 6) & 127, ic = t & 63;
        W1p[t] = (f16)w_off[(oc * 64 + ic) * 9 + tap];
    } else {
        int t2 = t - 73728;
        int tap = t2 >> 12, oc = (t2 >> 6) & 63, ic = t2 & 63;
        W2p[t2] = (f16)w_conv[(oc * 64 + ic) * 9 + tap];
    }
}

// ---------------- x NCHW fp32 -> xT NHWC f16 ----------------
__global__ __launch_bounds__(256) void transpose_k(
    const float* __restrict__ x, f16* __restrict__ xT)
{
    __shared__ float lds[64 * 132];
    const int b = blockIdx.x >> 7, h = blockIdx.x & 127;
    const int tid = threadIdx.x;
    const float4* x4 = (const float4*)x;
    for (int i = tid; i < 2048; i += 256) {
        int ic = i >> 5, wq = i & 31;
        float4 v = x4[(b * 64 + ic) * 4096 + h * 32 + wq];
        *(float4*)&lds[ic * 132 + wq * 4] = v;
    }
    __syncthreads();
    for (int i = tid; i < 1024; i += 256) {
        int w = i & 127, kg = i >> 7;
        half8 hv;
        #pragma unroll
        for (int j = 0; j < 8; ++j) hv[j] = (f16)lds[(kg * 8 + j) * 132 + w];
        *(half8*)&xT[(((size_t)(b * 128 + h) * 128 + w) << 6) + kg * 8] = hv;
    }
}

__device__ __forceinline__ float bilin(const float* __restrict__ xp, float rr, float cc) {
    rr = fminf(fmaxf(rr, 0.f), 127.f);
    cc = fminf(fmaxf(cc, 0.f), 127.f);
    const float r0f = floorf(rr), c0f = floorf(cc);
    const float r1f = ceilf(rr),  c1f = ceilf(cc);
    const int r0 = (int)r0f, r1 = (int)r1f, c0 = (int)c0f, c1 = (int)c1f;
    const float v_lt = xp[(r0 << 7) + c0];
    const float v_rt = xp[(r1 << 7) + c0];
    const float v_lb = xp[(r0 << 7) + c1];
    const float v_rb = xp[(r1 << 7) + c1];
    const float fr = rr - r0f, fc = cc - c0f;
    const float vt = fr * (v_rt - v_lt) + v_lt;
    const float vb = fr * (v_rb - v_lb) + v_lb;
    return fc * (vb - vt) + vt;
}

// ---------------- fused conv1 (implicit GEMM) + deformable gather ----------------
// Block (t, b): conv1 src rows 2t, 2t+1, all 128 oc  ==> deform output rows t
// (even oc) and t+64 (odd oc), all 64 channels. No off buffer.
// LDS (66560 B): phase 1 = x tile 4 rows x 130 cols x 64 ic f16 swizzled;
//                phase 2 = conv1 results cres[u][w][130] f16 (u = row-in-pair).
__global__ __launch_bounds__(256, 2) void conv1_deform_k(
    const f16* __restrict__ xT, const float* __restrict__ x,
    const f16* __restrict__ Wp, f16* __restrict__ mapped)
{
    __shared__ char lds[66560];
    ushort_t* cres = (ushort_t*)lds;

    const int tid = threadIdx.x;
    const int t = blockIdx.x;          // 0..63
    const int b = blockIdx.y;

    // ---- stage rows 2t-1 .. 2t+2, swizzled ----
    {
        const i32x4* s4 = (const i32x4*)xT;
        for (int s = tid; s < 4160; s += 256) {       // 4*130*8 slots
            int kg = s & 7, q = s >> 3;
            int c = q % 130, r = q / 130;
            int rowg = 2 * t + r - 1, wg = c - 1;
            i32x4 v = {0, 0, 0, 0};
            if ((unsigned)rowg < 128u && (unsigned)wg < 128u)
                v = s4[((b * 128 + rowg) * 128 + wg) * 8 + kg];
            int off = (q << 7) + (kg << 4);
            off ^= (c & 7) << 4;
            *(i32x4*)(lds + off) = v;
        }
    }
    __syncthreads();

    const int lane = tid & 63, wv = tid >> 6;
    const int l15 = lane & 15, l4 = lane >> 4;
    const int wm = wv >> 1, u = wv & 1;     // 2M x 2N; wave owns output row u
    const int ocbA = wm * 64 + l15;

    f32x4 acc[4][8];
    #pragma unroll
    for (int m = 0; m < 4; ++m)
        #pragma unroll
        for (int n = 0; n < 8; ++n) acc[m][n] = {0.f, 0.f, 0.f, 0.f};

    half8 a_cur[4], a_nxt[4];
    #pragma unroll
    for (int m = 0; m < 4; ++m)
        a_cur[m] = *(const half8*)&Wp[(0 * 128 + ocbA + m * 16) * 64 + l4 * 8];

    #pragma unroll
    for (int step = 0; step < 18; ++step) {
        const int tap = step >> 1, ks = step & 1;
        const int ky = tap / 3, kx = tap % 3;
        if (step < 17) {
            const int tap1 = (step + 1) >> 1, ks1 = (step + 1) & 1;
            #pragma unroll
            for (int m = 0; m < 4; ++m)
                a_nxt[m] = *(const half8*)&Wp[(tap1 * 128 + ocbA + m * 16) * 64 + ks1 * 32 + l4 * 8];
        }
        half8 bf[8];
        #pragma unroll
        for (int n = 0; n < 8; ++n) {
            const int c = n * 16 + l15 + kx;
            int off = (((u + ky) * 130 + c) << 7) + (ks << 6) + (l4 << 4);
            off ^= (c & 7) << 4;
            bf[n] = *(const half8*)(lds + off);
        }
        #pragma unroll
        for (int m = 0; m < 4; ++m)
            #pragma unroll
            for (int n = 0; n < 8; ++n)
                acc[m][n] = __builtin_amdgcn_mfma_f32_16x16x32_f16(
                    a_cur[m], bf[n], acc[m][n], 0, 0, 0);
        #pragma unroll
        for (int m = 0; m < 4; ++m) a_cur[m] = a_nxt[m];
    }

    __syncthreads();   // x tile dead; reuse LDS for conv1 results

    // ---- park conv1 results in LDS as f16: cres[u][w][130] (ch index) ----
    // C/D layout: col(pix within 16) = l15, row(oc within 16) = l4*4 + i.
    #pragma unroll
    for (int m = 0; m < 4; ++m) {
        const int oc0 = wm * 64 + m * 16 + l4 * 4;
        #pragma unroll
        for (int n = 0; n < 8; ++n) {
            const int w = n * 16 + l15;
            const int base = (u * 128 + w) * 130 + oc0;
            f16x2 p0; p0[0] = (f16)acc[m][n][0]; p0[1] = (f16)acc[m][n][1];
            f16x2 p1; p1[0] = (f16)acc[m][n][2]; p1[1] = (f16)acc[m][n][3];
            *(f16x2*)&cres[base]     = p0;
            *(f16x2*)&cres[base + 2] = p1;
        }
    }
    __syncthreads();

    // ---- deform: wave wv -> w_out = (wv&1)*64 + lane, channels (wv>>1)*32 .. +31
    {
        const int half_ = wv & 1;
        const int w_out = half_ * 64 + lane;
        const int wq = 2 * lane;            // src col of pixel 2*w_out (row-in-pair = half_)
        const int c0 = (wv >> 1) * 32;
        const size_t mbase = ((size_t)b << 14);

        #pragma unroll 4
        for (int cc = 0; cc < 32; ++cc) {
            const int c = c0 + cc;
            // ch 2c (lo) = even-oc path (out row t); ch 2c+1 (hi) = odd-oc path (row t+64)
            const f16x2 R = *(const f16x2*)&cres[(half_ * 128 + wq) * 130 + 2 * c];
            const f16x2 Cf = *(const f16x2*)&cres[(half_ * 128 + wq + 1) * 130 + 2 * c];
            const float* xp = x + (((size_t)b * 64 + c) << 14);
            const float v0 = bilin(xp, (float)R[0] + (float)t,        (float)Cf[0] + (float)w_out);
            const float v1 = bilin(xp, (float)R[1] + (float)(t + 64), (float)Cf[1] + (float)w_out);
            mapped[(mbase + (size_t)t * 128 + w_out) * 64 + c]          = (f16)v0;
            mapped[(mbase + (size_t)(t + 64) * 128 + w_out) * 64 + c]   = (f16)v1;
        }
    }
}

// ---------------- conv2: implicit GEMM, 2 output rows per block ----------------
// src: mapped NHWC f16. Wp: [9][64][64]. out: NCHW fp32 + bias.
__global__ __launch_bounds__(256, 2) void conv2_k(
    const f16* __restrict__ src, const f16* __restrict__ Wp,
    const float* __restrict__ bias, float* __restrict__ out)
{
    __shared__ char lds[66560];
    const int tid = threadIdx.x;
    const int s = blockIdx.x;          // output rows 2s, 2s+1
    const int b = blockIdx.y;

    {
        const i32x4* s4 = (const i32x4*)src;
        for (int i = tid; i < 4160; i += 256) {
            int kg = i & 7, q = i >> 3;
            int c = q % 130, r = q / 130;
            int rowg = 2 * s + r - 1, wg = c - 1;
            i32x4 v = {0, 0, 0, 0};
            if ((unsigned)rowg < 128u && (unsigned)wg < 128u)
                v = s4[((b * 128 + rowg) * 128 + wg) * 8 + kg];
            int off = (q << 7) + (kg << 4);
            off ^= (c & 7) << 4;
            *(i32x4*)(lds + off) = v;
        }
    }
    __syncthreads();

    const int lane = tid & 63, wv = tid >> 6;
    const int l15 = lane & 15, l4 = lane >> 4;
    const int u = wv >> 1, pixb = (wv & 1) * 64;   // wave: row u, col half

    f32x4 acc[4][4];
    #pragma unroll
    for (int m = 0; m < 4; ++m)
        #pragma unroll
        for (int n = 0; n < 4; ++n) acc[m][n] = {0.f, 0.f, 0.f, 0.f};

    // 3-slot rotating A prefetch (2 steps ahead; weights L2-resident)
    half8 ab[3][4];
    #pragma unroll
    for (int m = 0; m < 4; ++m) {
        ab[0][m] = *(const half8*)&Wp[(0 * 64 + l15 + m * 16) * 64 + 0 * 32 + l4 * 8];
        ab[1][m] = *(const half8*)&Wp[(0 * 64 + l15 + m * 16) * 64 + 1 * 32 + l4 * 8];
    }

    #pragma unroll
    for (int step = 0; step < 18; ++step) {
        const int tap = step >> 1, ks = step & 1;
        const int ky = tap / 3, kx = tap % 3;
        if (step < 16) {
            const int tap2 = (step + 2) >> 1, ks2 = (step + 2) & 1;
            #pragma unroll
            for (int m = 0; m < 4; ++m)
                ab[(step + 2) % 3][m] =
                    *(const half8*)&Wp[(tap2 * 64 + l15 + m * 16) * 64 + ks2 * 32 + l4 * 8];
        }
        half8 bf[4];
        #pragma unroll
        for (int n = 0; n < 4; ++n) {
            const int c = pixb + n * 16 + l15 + kx;
            int off = (((u + ky) * 130 + c) << 7) + (ks << 6) + (l4 << 4);
            off ^= (c & 7) << 4;
            bf[n] = *(const half8*)(lds + off);
        }
        #pragma unroll
        for (int m = 0; m < 4; ++m)
            #pragma unroll
            for (int n = 0; n < 4; ++n)
                acc[m][n] = __builtin_amdgcn_mfma_f32_16x16x32_f16(
                    ab[step % 3][m], bf[n], acc[m][n], 0, 0, 0);
    }

    const int orow = 2 * s + u;
    #pragma unroll
    for (int m = 0; m < 4; ++m) {
        #pragma unroll
        for (int i = 0; i < 4; ++i) {
            const int oc = m * 16 + l4 * 4 + i;
            const float bb = bias[oc];
            #pragma unroll
            for (int n = 0; n < 4; ++n) {
                const int pix = pixb + n * 16 + l15;
                out[(((size_t)b * 64 + oc) << 14) + orow * 128 + pix] = acc[m][n][i] + bb;
            }
        }
    }
}

extern "C" void kernel_launch(void* const* d_in, const int* in_sizes, int n_in,
                              void* d_out, int out_size, void* d_ws, size_t ws_size,
                              hipStream_t stream) {
    const float* x      = (const float*)d_in[0];
    const float* w_off  = (const float*)d_in[1];
    const float* w_conv = (const float*)d_in[2];
    const float* b_conv = (const float*)d_in[3];
    float* out = (float*)d_out;

    char* ws = (char*)d_ws;
    f16* xT     = (f16*)ws;                          // 33,554,432 B
    f16* mapped = (f16*)(ws + 33554432);             // 33,554,432 B (NOT aliased: fused kernel reads xT)
    f16* W1p    = (f16*)(ws + 67108864);             // 147,456 B
    f16* W2p    = (f16*)(ws + 67108864 + 147456);    // 73,728 B

    pack_w_k<<<432, 256, 0, stream>>>(w_off, w_conv, W1p, W2p);
    transpose_k<<<2048, 256, 0, stream>>>(x, xT);
    conv1_deform_k<<<dim3(64, 16), 256, 0, stream>>>(xT, x, W1p, mapped);
    conv2_k<<<dim3(64, 16), 256, 0, stream>>>(mapped, W2p, b_conv, out);
}

// Round 5
// 271.644 us; speedup vs baseline: 8.3794x; 1.1457x over previous
//
#include <hip/hip_runtime.h>

typedef _Float16 f16;
typedef _Float16 half8 __attribute__((ext_vector_type(8)));
typedef _Float16 f16x2 __attribute__((ext_vector_type(2)));
typedef float f32x4 __attribute__((ext_vector_type(4)));
typedef int i32x4 __attribute__((ext_vector_type(4)));
typedef unsigned short ushort_t;

// B=16, C=64, H=W=128, OUT=64, HW=16384

// ---------------- weight packing: OIHW fp32 -> [tap][oc][ic] f16 ----------------
__global__ __launch_bounds__(256) void pack_w_k(
    const float* __restrict__ w_off, const float* __restrict__ w_conv,
    f16* __restrict__ W1p, f16* __restrict__ W2p)
{
    int t = blockIdx.x * 256 + threadIdx.x;   // 432*256 = 110592 = 73728 + 36864
    if (t < 73728) {
        int tap = t >> 13, oc = (t >> 6) & 127, ic = t & 63;
        W1p[t] = (f16)w_off[(oc * 64 + ic) * 9 + tap];
    } else {
        int t2 = t - 73728;
        int tap = t2 >> 12, oc = (t2 >> 6) & 63, ic = t2 & 63;
        W2p[t2] = (f16)w_conv[(oc * 64 + ic) * 9 + tap];
    }
}

// ---------------- x NCHW fp32 -> xT NHWC f16 ----------------
__global__ __launch_bounds__(256) void transpose_k(
    const float* __restrict__ x, f16* __restrict__ xT)
{
    __shared__ float lds[64 * 132];
    const int b = blockIdx.x >> 7, h = blockIdx.x & 127;
    const int tid = threadIdx.x;
    const float4* x4 = (const float4*)x;
    for (int i = tid; i < 2048; i += 256) {
        int ic = i >> 5, wq = i & 31;
        float4 v = x4[(b * 64 + ic) * 4096 + h * 32 + wq];
        *(float4*)&lds[ic * 132 + wq * 4] = v;
    }
    __syncthreads();
    for (int i = tid; i < 1024; i += 256) {
        int w = i & 127, kg = i >> 7;
        half8 hv;
        #pragma unroll
        for (int j = 0; j < 8; ++j) hv[j] = (f16)lds[(kg * 8 + j) * 132 + w];
        *(half8*)&xT[(((size_t)(b * 128 + h) * 128 + w) << 6) + kg * 8] = hv;
    }
}

__device__ __forceinline__ float bilin(const float* __restrict__ xp, float rr, float cc) {
    rr = fminf(fmaxf(rr, 0.f), 127.f);
    cc = fminf(fmaxf(cc, 0.f), 127.f);
    const float r0f = floorf(rr), c0f = floorf(cc);
    const float r1f = ceilf(rr),  c1f = ceilf(cc);
    const int r0 = (int)r0f, r1 = (int)r1f, c0 = (int)c0f, c1 = (int)c1f;
    const float v_lt = xp[(r0 << 7) + c0];
    const float v_rt = xp[(r1 << 7) + c0];
    const float v_lb = xp[(r0 << 7) + c1];
    const float v_rb = xp[(r1 << 7) + c1];
    const float fr = rr - r0f, fc = cc - c0f;
    const float vt = fr * (v_rt - v_lt) + v_lt;
    const float vb = fr * (v_rb - v_lb) + v_lb;
    return fc * (vb - vt) + vt;
}

// ---------------- fused conv1 (implicit GEMM, one src row) + deform gather ----
// Block (sr, b): conv1 output row sr (all 128 oc). With t=sr>>1, u=sr&1 this
// serves deform outputs h_out in {t, t+64}, w_out in u*64+[0,64), all 64 ch.
// (src row needed by deform = 2*(h_out mod 64) + (w_out>=64) = 2t+u = sr.)
// LDS phase 1: x tile [3 rows][130 cols][64 ic] f16, XOR-swizzled (49920 B).
// LDS phase 2 (reuse): cres[pix 0..127][ch 0..127] ushort, pitch 130 (33280 B).
__global__ __launch_bounds__(256, 3) void conv1_deform_k(
    const f16* __restrict__ xT, const float* __restrict__ x,
    const f16* __restrict__ Wp, f16* __restrict__ mapped)
{
    __shared__ char lds[49920];
    ushort_t* cres = (ushort_t*)lds;

    const int tid = threadIdx.x;
    const int sr = blockIdx.x;          // src row 0..127
    const int b = blockIdx.y;
    const int t = sr >> 1, u = sr & 1;

    // ---- stage xT rows sr-1..sr+1, swizzled ----
    {
        const i32x4* s4 = (const i32x4*)xT;
        for (int s = tid; s < 3120; s += 256) {       // 3*130*8 16B-slots
            int kg = s & 7, q = s >> 3;
            int c = q % 130, r = q / 130;
            int rowg = sr + r - 1, wg = c - 1;
            i32x4 v = {0, 0, 0, 0};
            if ((unsigned)rowg < 128u && (unsigned)wg < 128u)
                v = s4[((b * 128 + rowg) * 128 + wg) * 8 + kg];
            int off = (q << 7) + (kg << 4);
            off ^= (c & 7) << 4;
            *(i32x4*)(lds + off) = v;
        }
    }
    __syncthreads();

    const int lane = tid & 63, wv = tid >> 6;
    const int l15 = lane & 15, l4 = lane >> 4;
    const int ocb = wv * 32 + l15;      // wave owns 32 ocs

    f32x4 acc[2][8];
    #pragma unroll
    for (int m = 0; m < 2; ++m)
        #pragma unroll
        for (int n = 0; n < 8; ++n) acc[m][n] = {0.f, 0.f, 0.f, 0.f};

    half8 a_cur[2], a_nxt[2];
    #pragma unroll
    for (int m = 0; m < 2; ++m)
        a_cur[m] = *(const half8*)&Wp[(0 * 128 + ocb + m * 16) * 64 + l4 * 8];

    #pragma unroll
    for (int step = 0; step < 18; ++step) {
        const int tap = step >> 1, ks = step & 1;
        const int ky = tap / 3, kx = tap % 3;
        if (step < 17) {
            const int tap1 = (step + 1) >> 1, ks1 = (step + 1) & 1;
            #pragma unroll
            for (int m = 0; m < 2; ++m)
                a_nxt[m] = *(const half8*)&Wp[(tap1 * 128 + ocb + m * 16) * 64 + ks1 * 32 + l4 * 8];
        }
        #pragma unroll
        for (int n = 0; n < 8; ++n) {
            const int c = n * 16 + l15 + kx;
            int off = ((ky * 130 + c) << 7) + (ks << 6) + (l4 << 4);
            off ^= (c & 7) << 4;
            const half8 bf = *(const half8*)(lds + off);
            acc[0][n] = __builtin_amdgcn_mfma_f32_16x16x32_f16(a_cur[0], bf, acc[0][n], 0, 0, 0);
            acc[1][n] = __builtin_amdgcn_mfma_f32_16x16x32_f16(a_cur[1], bf, acc[1][n], 0, 0, 0);
        }
        #pragma unroll
        for (int m = 0; m < 2; ++m) a_cur[m] = a_nxt[m];
    }

    __syncthreads();   // x tile dead; reuse LDS for conv1 results

    // ---- park conv1 row as f16: cres[pix][ch], pitch 130 ----
    // C/D layout: col(pix within 16) = l15, row(oc within 16) = l4*4 + i.
    #pragma unroll
    for (int m = 0; m < 2; ++m) {
        const int oc0 = wv * 32 + m * 16 + l4 * 4;
        #pragma unroll
        for (int n = 0; n < 8; ++n) {
            const int pix = n * 16 + l15;
            const int base = pix * 130 + oc0;
            f16x2 p0; p0[0] = (f16)acc[m][n][0]; p0[1] = (f16)acc[m][n][1];
            f16x2 p1; p1[0] = (f16)acc[m][n][2]; p1[1] = (f16)acc[m][n][3];
            *(f16x2*)&cres[base]     = p0;
            *(f16x2*)&cres[base + 2] = p1;
        }
    }
    __syncthreads();

    // ---- gather: thread -> (hsel, c-half, w_off) ----
    {
        const int hsel = tid >> 7;             // 0: h_out=t (ch 2c), 1: h_out=t+64 (ch 2c+1)
        const int c0 = ((tid >> 6) & 1) * 32;
        const int w_off = tid & 63;
        const int w_out = u * 64 + w_off;
        const int h_out = t + hsel * 64;
        const int wq = 2 * w_off;
        const float hb = (float)h_out, wb = (float)w_out;
        f16* mp = mapped + ((((size_t)b << 14) + h_out * 128 + w_out) << 6) + c0;

        #pragma unroll
        for (int j = 0; j < 4; ++j) {
            half8 ov;
            #pragma unroll
            for (int e = 0; e < 8; ++e) {
                const int c = c0 + j * 8 + e;
                // BIT-reinterpret the parked f16 (value-cast was the r4 bug)
                const float R  = (float)*(const f16*)&cres[wq * 130 + 2 * c + hsel];
                const float Cf = (float)*(const f16*)&cres[(wq + 1) * 130 + 2 * c + hsel];
                const float* xp = x + (((size_t)b * 64 + c) << 14);
                ov[e] = (f16)bilin(xp, R + hb, Cf + wb);
            }
            *(half8*)&mp[j * 8] = ov;
        }
    }
}

// ---------------- conv2: implicit GEMM, one output row per block ----------------
// src: mapped NHWC f16. Wp: [9][64][64]. out: NCHW fp32 + bias.
__global__ __launch_bounds__(256, 3) void conv2_k(
    const f16* __restrict__ src, const f16* __restrict__ Wp,
    const float* __restrict__ bias, float* __restrict__ out)
{
    __shared__ char lds[49920];
    const int tid = threadIdx.x;
    const int h = blockIdx.x;
    const int b = blockIdx.y;

    {
        const i32x4* s4 = (const i32x4*)src;
        for (int s = tid; s < 3120; s += 256) {
            int kg = s & 7, q = s >> 3;
            int c = q % 130, r = q / 130;
            int rowg = h + r - 1, wg = c - 1;
            i32x4 v = {0, 0, 0, 0};
            if ((unsigned)rowg < 128u && (unsigned)wg < 128u)
                v = s4[((b * 128 + rowg) * 128 + wg) * 8 + kg];
            int off = (q << 7) + (kg << 4);
            off ^= (c & 7) << 4;
            *(i32x4*)(lds + off) = v;
        }
    }
    __syncthreads();

    const int lane = tid & 63, wv = tid >> 6;
    const int l15 = lane & 15, l4 = lane >> 4;
    const int wm = wv >> 1, wn = wv & 1;     // wave: 32 oc x 64 pix
    const int ocb = wm * 32 + l15;
    const int pixb = wn * 64;

    f32x4 acc[2][4];
    #pragma unroll
    for (int m = 0; m < 2; ++m)
        #pragma unroll
        for (int n = 0; n < 4; ++n) acc[m][n] = {0.f, 0.f, 0.f, 0.f};

    half8 a_cur[2], a_nxt[2];
    #pragma unroll
    for (int m = 0; m < 2; ++m)
        a_cur[m] = *(const half8*)&Wp[(0 * 64 + ocb + m * 16) * 64 + l4 * 8];

    #pragma unroll
    for (int step = 0; step < 18; ++step) {
        const int tap = step >> 1, ks = step & 1;
        const int ky = tap / 3, kx = tap % 3;
        if (step < 17) {
            const int tap1 = (step + 1) >> 1, ks1 = (step + 1) & 1;
            #pragma unroll
            for (int m = 0; m < 2; ++m)
                a_nxt[m] = *(const half8*)&Wp[(tap1 * 64 + ocb + m * 16) * 64 + ks1 * 32 + l4 * 8];
        }
        #pragma unroll
        for (int n = 0; n < 4; ++n) {
            const int c = pixb + n * 16 + l15 + kx;
            int off = ((ky * 130 + c) << 7) + (ks << 6) + (l4 << 4);
            off ^= (c & 7) << 4;
            const half8 bf = *(const half8*)(lds + off);
            acc[0][n] = __builtin_amdgcn_mfma_f32_16x16x32_f16(a_cur[0], bf, acc[0][n], 0, 0, 0);
            acc[1][n] = __builtin_amdgcn_mfma_f32_16x16x32_f16(a_cur[1], bf, acc[1][n], 0, 0, 0);
        }
        #pragma unroll
        for (int m = 0; m < 2; ++m) a_cur[m] = a_nxt[m];
    }

    #pragma unroll
    for (int m = 0; m < 2; ++m) {
        #pragma unroll
        for (int i = 0; i < 4; ++i) {
            const int oc = wm * 32 + m * 16 + l4 * 4 + i;
            const float bb = bias[oc];
            #pragma unroll
            for (int n = 0; n < 4; ++n) {
                const int pix = pixb + n * 16 + l15;
                out[(((size_t)b * 64 + oc) << 14) + h * 128 + pix] = acc[m][n][i] + bb;
            }
        }
    }
}

extern "C" void kernel_launch(void* const* d_in, const int* in_sizes, int n_in,
                              void* d_out, int out_size, void* d_ws, size_t ws_size,
                              hipStream_t stream) {
    const float* x      = (const float*)d_in[0];
    const float* w_off  = (const float*)d_in[1];
    const float* w_conv = (const float*)d_in[2];
    const float* b_conv = (const float*)d_in[3];
    float* out = (float*)d_out;

    char* ws = (char*)d_ws;
    f16* xT     = (f16*)ws;                          // 33,554,432 B
    f16* mapped = (f16*)(ws + 33554432);             // 33,554,432 B
    f16* W1p    = (f16*)(ws + 67108864);             // 147,456 B
    f16* W2p    = (f16*)(ws + 67108864 + 147456);    // 73,728 B

    pack_w_k<<<432, 256, 0, stream>>>(w_off, w_conv, W1p, W2p);
    transpose_k<<<2048, 256, 0, stream>>>(x, xT);
    conv1_deform_k<<<dim3(128, 16), 256, 0, stream>>>(xT, x, W1p, mapped);
    conv2_k<<<dim3(128, 16), 256, 0, stream>>>(mapped, W2p, b_conv, out);
}